// Round 1
// 868.935 us; speedup vs baseline: 1.5546x; 1.5546x over previous
//
#include <hip/hip_runtime.h>
#include <stdint.h>

#define B_  4
#define EH_ 512
#define T_  256
#define PH_ 320
#define U_  128
#define JH_ 512
#define NC_ 1025

typedef __attribute__((ext_vector_type(8))) short short8;
typedef __attribute__((ext_vector_type(4))) short short4v;
typedef __attribute__((ext_vector_type(4))) float floatx4;

__device__ __forceinline__ unsigned short f2bf(float f) {
    unsigned int x = __float_as_uint(f);
    x += 0x7fffu + ((x >> 16) & 1u);
    return (unsigned short)(x >> 16);
}
__device__ __forceinline__ float bf2f(unsigned short u) {
    return __uint_as_float(((unsigned int)u) << 16);
}

// ---------------- P1: e = enc^T @ W_enc + b_enc  -> [B*T, JH] fp32 -----------
__global__ __launch_bounds__(512) void enc_proj(const float* __restrict__ enc,
                                                const float* __restrict__ W_enc,
                                                const float* __restrict__ b_enc,
                                                float* __restrict__ e_out) {
    __shared__ float a_lds[8][EH_];
    const int tid = threadIdx.x;
    const int mb = blockIdx.x * 8;   // rows m = b*T + t ; 8 consecutive t, same b
    const int b  = mb >> 8;          // /T_
    const int t0 = mb & (T_ - 1);
    {
        const float* src = enc + ((size_t)(b * EH_ + tid) * T_ + t0);
        float4 v0 = *(const float4*)(src);
        float4 v1 = *(const float4*)(src + 4);
        a_lds[0][tid] = v0.x; a_lds[1][tid] = v0.y; a_lds[2][tid] = v0.z; a_lds[3][tid] = v0.w;
        a_lds[4][tid] = v1.x; a_lds[5][tid] = v1.y; a_lds[6][tid] = v1.z; a_lds[7][tid] = v1.w;
    }
    __syncthreads();
    float acc[8];
    const float bias = b_enc[tid];
#pragma unroll
    for (int i = 0; i < 8; i++) acc[i] = bias;
    for (int k4 = 0; k4 < EH_ / 4; k4++) {
        const float w0 = W_enc[(k4 * 4 + 0) * JH_ + tid];
        const float w1 = W_enc[(k4 * 4 + 1) * JH_ + tid];
        const float w2 = W_enc[(k4 * 4 + 2) * JH_ + tid];
        const float w3 = W_enc[(k4 * 4 + 3) * JH_ + tid];
#pragma unroll
        for (int i = 0; i < 8; i++) {
            float4 a = *(const float4*)(&a_lds[i][k4 * 4]);
            acc[i] = fmaf(a.x, w0, acc[i]);
            acc[i] = fmaf(a.y, w1, acc[i]);
            acc[i] = fmaf(a.z, w2, acc[i]);
            acc[i] = fmaf(a.w, w3, acc[i]);
        }
    }
#pragma unroll
    for (int i = 0; i < 8; i++) e_out[(mb + i) * JH_ + tid] = acc[i];
}

// ---------------- P2: p = dec^T @ W_pred + b_pred -> [B*U, JH] fp32 ----------
__global__ __launch_bounds__(512) void pred_proj(const float* __restrict__ dec,
                                                 const float* __restrict__ W_pred,
                                                 const float* __restrict__ b_pred,
                                                 float* __restrict__ p_out) {
    __shared__ float a_lds[8][PH_];
    const int tid = threadIdx.x;
    const int mb = blockIdx.x * 8;   // rows m = b*U + u
    const int b  = mb >> 7;          // /U_
    const int u0 = mb & (U_ - 1);
    if (tid < PH_) {
        const float* src = dec + ((size_t)(b * PH_ + tid) * U_ + u0);
        float4 v0 = *(const float4*)(src);
        float4 v1 = *(const float4*)(src + 4);
        a_lds[0][tid] = v0.x; a_lds[1][tid] = v0.y; a_lds[2][tid] = v0.z; a_lds[3][tid] = v0.w;
        a_lds[4][tid] = v1.x; a_lds[5][tid] = v1.y; a_lds[6][tid] = v1.z; a_lds[7][tid] = v1.w;
    }
    __syncthreads();
    float acc[8];
    const float bias = b_pred[tid];
#pragma unroll
    for (int i = 0; i < 8; i++) acc[i] = bias;
    for (int k4 = 0; k4 < PH_ / 4; k4++) {
        const float w0 = W_pred[(k4 * 4 + 0) * JH_ + tid];
        const float w1 = W_pred[(k4 * 4 + 1) * JH_ + tid];
        const float w2 = W_pred[(k4 * 4 + 2) * JH_ + tid];
        const float w3 = W_pred[(k4 * 4 + 3) * JH_ + tid];
#pragma unroll
        for (int i = 0; i < 8; i++) {
            float4 a = *(const float4*)(&a_lds[i][k4 * 4]);
            acc[i] = fmaf(a.x, w0, acc[i]);
            acc[i] = fmaf(a.y, w1, acc[i]);
            acc[i] = fmaf(a.z, w2, acc[i]);
            acc[i] = fmaf(a.w, w3, acc[i]);
        }
    }
#pragma unroll
    for (int i = 0; i < 8; i++) p_out[(mb + i) * JH_ + tid] = acc[i];
}

// ---------------- P3: WT2 = swizzled bf16 W_out for coalesced B-frag loads ---
// Main region (cols 0..1023), ushort index:
//   ((c>>4)*16 + (k>>5))*512 + ((k>>3)&3)*128 + (c&15)*8 + (k&7)
// so a wave's fragment load (fixed col-tile ct=c>>4, k-block kb=k>>5) is
// one contiguous 1 KiB: lane (qd*16+ln) reads 16 B at lane*8 ushorts.
// Tail region at offset 524288: plain row for col 1024 (WTrow[k]).
__global__ __launch_bounds__(256) void wt_prep(const float* __restrict__ W_out,
                                               unsigned short* __restrict__ WT2) {
    const int idx = blockIdx.x * 256 + threadIdx.x;   // [0, 524288)
    const int k = idx >> 10;
    const int c = idx & 1023;
    const float v = W_out[(size_t)k * NC_ + c];
    const int dst = ((c >> 4) * 16 + (k >> 5)) * 512 +
                    ((k >> 3) & 3) * 128 + (c & 15) * 8 + (k & 7);
    WT2[dst] = f2bf(v);
    if (idx < JH_) WT2[524288 + idx] = f2bf(W_out[(size_t)idx * NC_ + (NC_ - 1)]);
}

// ---------------- Main fused joint: logits + log_softmax, single pass --------
// grid = 2048 blocks x 512 threads. Block: 64 rows (one (b,t), u0..u0+63).
// Wave w owns columns [w*128, w*128+128).
// Epilogue: stage 8 rows at a time in LDS (aliased over dead h_lds) and write
// the block's contiguous 262,400 B output span densely with float4 NT stores
// (span is 2050 x 128 B, line-aligned -> zero partial-sector RMW).
__global__ __launch_bounds__(512, 2) void joint_kernel(
        const float* __restrict__ e, const float* __restrict__ p,
        const unsigned short* __restrict__ WT2,
        const float* __restrict__ b_out, float* __restrict__ out) {
    __shared__ __align__(16) char hs_buf[8 * NC_ * 4];  // 32,800 B: h_lds (32,768) U stage
    __shared__ float stripes[8][64];
    __shared__ float rowmax_lds[64];
    __shared__ float lse_lds[64];
    __shared__ float c1024_lds[64];
    unsigned short* h_lds = (unsigned short*)hs_buf;    // [64][256] bf16, XOR-swizzled
    float* stage = (float*)hs_buf;                      // [8][1025] f32 (epilogue only)

    const int tid = threadIdx.x;
    const int m0 = blockIdx.x * 64;
    const int bb = m0 >> 15;             // /(T*U)
    const int tt = (m0 >> 7) & (T_ - 1);
    const int u0 = m0 & (U_ - 1);        // 0 or 64

    const int wave = tid >> 6;
    const int lane = tid & 63;
    const int qd = lane >> 4;
    const int ln = lane & 15;
    const int n0 = wave << 7;

    floatx4 acc[4][8];
#pragma unroll
    for (int i = 0; i < 4; i++)
#pragma unroll
        for (int nt = 0; nt < 8; nt++) acc[i][nt] = (floatx4){0.f, 0.f, 0.f, 0.f};

    const float* e_row = e + (size_t)(bb * T_ + tt) * JH_;
    const float* p_base = p + (size_t)(bb * U_ + u0) * JH_;
    const unsigned short* wt_wave = WT2 + (size_t)wave * 65536 + lane * 8;
    const unsigned short* wt_c1024 = WT2 + 524288;

    float c1024_part = 0.0f;
    const int rr = tid >> 3;   // row for col-1024 dot (8 threads/row)
    const int g  = tid & 7;

    // staging: thread = (k-quad kq = lane, row-slot rslot = wave)
    // element (r, kk) lives at h_lds[r*256 + ((kk>>3)^(r&7))*8 + (kk&7)]
    // with r = it*8 + rslot, (r&7) == rslot -> swizzle is loop-invariant.
    const int kq = lane;
    const int rslot = wave;
    unsigned short* h_st = h_lds + rslot * 256 + (((kq >> 1) ^ rslot) * 8) + (kq & 1) * 4;

    for (int ph = 0; ph < 2; ph++) {
        const int kbase = ph * 256;
        // ---- stage h = relu(e + p) as bf16, swizzled; float4 loads, b64 LDS writes ----
        const float4 e4 = *(const float4*)(e_row + kbase + kq * 4);
        const float* p_ptr = p_base + (size_t)rslot * JH_ + kbase + kq * 4;
#pragma unroll
        for (int it = 0; it < 8; it++) {
            float4 pv = *(const float4*)(p_ptr + (size_t)it * 8 * JH_);
            short4v hw;
            hw[0] = (short)f2bf(fmaxf(e4.x + pv.x, 0.f));
            hw[1] = (short)f2bf(fmaxf(e4.y + pv.y, 0.f));
            hw[2] = (short)f2bf(fmaxf(e4.z + pv.z, 0.f));
            hw[3] = (short)f2bf(fmaxf(e4.w + pv.w, 0.f));
            *(short4v*)(h_st + it * 8 * 256) = hw;
        }
        __syncthreads();
        // ---- K loop: 8 steps of 32 ----
        for (int ks = 0; ks < 8; ks++) {
            const int k0l = ks * 32;
            const int kb = ph * 8 + ks;
            short8 a[4];
#pragma unroll
            for (int i = 0; i < 4; i++) {
                int m = i * 16 + ln;
                int pc = ((k0l >> 3) + qd) ^ (m & 7);
                a[i] = *(const short8*)(&h_lds[m * 256 + pc * 8]);
            }
#pragma unroll
            for (int nt = 0; nt < 8; nt++) {
                // coalesced: 64 lanes read one contiguous 1 KiB chunk
                const short8 bfrag = *(const short8*)(wt_wave + (size_t)nt * 8192 + kb * 512);
#pragma unroll
                for (int i = 0; i < 4; i++)
                    acc[i][nt] = __builtin_amdgcn_mfma_f32_16x16x32_bf16(
                            a[i], bfrag, acc[i][nt], 0, 0, 0);
            }
        }
        // ---- column 1024 partial dot (VALU) ----
#pragma unroll
        for (int cc = 0; cc < 4; cc++) {
            int c = g * 4 + cc;
            int pc = c ^ (rr & 7);
#pragma unroll
            for (int o = 0; o < 8; o++) {
                c1024_part += bf2f(h_lds[rr * 256 + pc * 8 + o]) *
                              bf2f(wt_c1024[kbase + c * 8 + o]);
            }
        }
        __syncthreads();   // before next-phase restage overwrites h_lds
    }

    // reduce col-1024 over the 8 threads of each row
    c1024_part += __shfl_down(c1024_part, 4, 8);
    c1024_part += __shfl_down(c1024_part, 2, 8);
    c1024_part += __shfl_down(c1024_part, 1, 8);

    // ---- bias add ----
#pragma unroll
    for (int nt = 0; nt < 8; nt++) {
        float bv = b_out[n0 + nt * 16 + ln];
#pragma unroll
        for (int i = 0; i < 4; i++) {
            acc[i][nt][0] += bv; acc[i][nt][1] += bv;
            acc[i][nt][2] += bv; acc[i][nt][3] += bv;
        }
    }

    // ---- row max (per lane over nt, then width-16 shuffle across columns) ----
    float mx[4][4];
#pragma unroll
    for (int i = 0; i < 4; i++)
#pragma unroll
        for (int r = 0; r < 4; r++) {
            float m = acc[i][0][r];
#pragma unroll
            for (int nt = 1; nt < 8; nt++) m = fmaxf(m, acc[i][nt][r]);
            m = fmaxf(m, __shfl_xor(m, 1, 16));
            m = fmaxf(m, __shfl_xor(m, 2, 16));
            m = fmaxf(m, __shfl_xor(m, 4, 16));
            m = fmaxf(m, __shfl_xor(m, 8, 16));
            mx[i][r] = m;
        }
    if (ln == 0) {
#pragma unroll
        for (int i = 0; i < 4; i++)
#pragma unroll
            for (int r = 0; r < 4; r++)
                stripes[wave][i * 16 + qd * 4 + r] = mx[i][r];
    }
    if (g == 0) c1024_lds[rr] = c1024_part + b_out[NC_ - 1];
    __syncthreads();
    if (tid < 64) {
        float m = c1024_lds[tid];
#pragma unroll
        for (int w = 0; w < 8; w++) m = fmaxf(m, stripes[w][tid]);
        rowmax_lds[tid] = m;
    }
    __syncthreads();

    // ---- sum of exp ----
#pragma unroll
    for (int i = 0; i < 4; i++)
#pragma unroll
        for (int r = 0; r < 4; r++) {
            float rm = rowmax_lds[i * 16 + qd * 4 + r];
            float s = 0.f;
#pragma unroll
            for (int nt = 0; nt < 8; nt++) s += __expf(acc[i][nt][r] - rm);
            s += __shfl_xor(s, 1, 16);
            s += __shfl_xor(s, 2, 16);
            s += __shfl_xor(s, 4, 16);
            s += __shfl_xor(s, 8, 16);
            mx[i][r] = s;  // reuse storage for stripe sums
        }
    if (ln == 0) {
#pragma unroll
        for (int i = 0; i < 4; i++)
#pragma unroll
            for (int r = 0; r < 4; r++)
                stripes[wave][i * 16 + qd * 4 + r] = mx[i][r];
    }
    __syncthreads();
    if (tid < 64) {
        float rm = rowmax_lds[tid];
        float s = __expf(c1024_lds[tid] - rm);
#pragma unroll
        for (int w = 0; w < 8; w++) s += stripes[w][tid];
        lse_lds[tid] = rm + __logf(s);
    }
    __syncthreads();

    // ---- write normalized logits: LDS-stage 8 rows, then dense float4 NT stores ----
    // chunk c covers rows [8c, 8c+8): i = c>>1, qd-pair = (c&1) ? {2,3} : {0,1}
#pragma unroll
    for (int c = 0; c < 8; c++) {
        const int i = c >> 1;
        if ((qd >> 1) == (c & 1)) {
#pragma unroll
            for (int r = 0; r < 4; r++) {
                const int lr = (qd & 1) * 4 + r;         // 0..7 within chunk
                const float l = lse_lds[c * 8 + lr];
#pragma unroll
                for (int nt = 0; nt < 8; nt++)
                    stage[lr * NC_ + n0 + nt * 16 + ln] = acc[i][nt][r] - l;
            }
        }
        if (tid < 8)
            stage[tid * NC_ + 1024] = c1024_lds[c * 8 + tid] - lse_lds[c * 8 + tid];
        __syncthreads();
        const floatx4* src4 = (const floatx4*)stage;
        floatx4* dst4 = (floatx4*)(out + (size_t)(m0 + c * 8) * NC_);
        for (int j = tid; j < (8 * NC_) / 4; j += 512)   // 2050 float4, contiguous span
            __builtin_nontemporal_store(src4[j], dst4 + j);
        __syncthreads();
    }
}

extern "C" void kernel_launch(void* const* d_in, const int* in_sizes, int n_in,
                              void* d_out, int out_size, void* d_ws, size_t ws_size,
                              hipStream_t stream) {
    const float* enc    = (const float*)d_in[0];
    const float* dec    = (const float*)d_in[1];
    const float* W_enc  = (const float*)d_in[2];
    const float* b_enc  = (const float*)d_in[3];
    const float* W_pred = (const float*)d_in[4];
    const float* b_pred = (const float*)d_in[5];
    const float* W_out  = (const float*)d_in[6];
    const float* b_out  = (const float*)d_in[7];
    float* out = (float*)d_out;

    char* ws = (char*)d_ws;
    float* e_buf = (float*)ws;                                 // 2 MiB: [1024][512] f32
    float* p_buf = (float*)(ws + (2u << 20));                  // 1 MiB: [512][512] f32
    unsigned short* WT2 = (unsigned short*)(ws + (3u << 20));  // ~1 MiB swizzled + col-1024 row

    enc_proj<<<dim3(128), dim3(512), 0, stream>>>(enc, W_enc, b_enc, e_buf);
    pred_proj<<<dim3(64), dim3(512), 0, stream>>>(dec, W_pred, b_pred, p_buf);
    wt_prep<<<dim3(2048), dim3(256), 0, stream>>>(W_out, WT2);
    joint_kernel<<<dim3(2048), dim3(512), 0, stream>>>(e_buf, p_buf, WT2, b_out, out);
}

// Round 2
// 788.341 us; speedup vs baseline: 1.7135x; 1.1022x over previous
//
#include <hip/hip_runtime.h>
#include <stdint.h>

#define B_  4
#define EH_ 512
#define T_  256
#define PH_ 320
#define U_  128
#define JH_ 512
#define NC_ 1025

typedef __attribute__((ext_vector_type(8))) short short8;
typedef __attribute__((ext_vector_type(4))) short short4v;
typedef __attribute__((ext_vector_type(4))) float floatx4;

__device__ __forceinline__ unsigned short f2bf(float f) {
    unsigned int x = __float_as_uint(f);
    x += 0x7fffu + ((x >> 16) & 1u);
    return (unsigned short)(x >> 16);
}
__device__ __forceinline__ float bf2f(unsigned short u) {
    return __uint_as_float(((unsigned int)u) << 16);
}

// ---------------- P1: e = enc^T @ W_enc + b_enc  -> [B*T, JH] fp32 -----------
// 4 rows/block (256 blocks = 1/CU) + 2-way k-split: quarters the per-CU
// LDS-broadcast read count vs the old 8-row full-K version.
__global__ __launch_bounds__(512) void enc_proj(const float* __restrict__ enc,
                                                const float* __restrict__ W_enc,
                                                const float* __restrict__ b_enc,
                                                float* __restrict__ e_out) {
    __shared__ float a_lds[4][EH_];
    __shared__ float pr[4][JH_];
    const int tid = threadIdx.x;
    const int mb = blockIdx.x * 4;   // rows m = b*T + t
    const int b  = mb >> 8;          // /T_
    const int t0 = mb & (T_ - 1);
    {
        const float* src = enc + ((size_t)(b * EH_ + tid) * T_ + t0);
        float4 v0 = *(const float4*)(src);
        a_lds[0][tid] = v0.x; a_lds[1][tid] = v0.y; a_lds[2][tid] = v0.z; a_lds[3][tid] = v0.w;
    }
    __syncthreads();
    const int j  = tid & 255;
    const int kh = tid >> 8;          // k-half
    const int kbase = kh * 256;
    float acc[4][2] = {{0.f, 0.f}, {0.f, 0.f}, {0.f, 0.f}, {0.f, 0.f}};
    for (int k4 = 0; k4 < 64; k4++) {
        const int k = kbase + k4 * 4;
        float w00 = W_enc[(k + 0) * JH_ + j], w01 = W_enc[(k + 0) * JH_ + j + 256];
        float w10 = W_enc[(k + 1) * JH_ + j], w11 = W_enc[(k + 1) * JH_ + j + 256];
        float w20 = W_enc[(k + 2) * JH_ + j], w21 = W_enc[(k + 2) * JH_ + j + 256];
        float w30 = W_enc[(k + 3) * JH_ + j], w31 = W_enc[(k + 3) * JH_ + j + 256];
#pragma unroll
        for (int i = 0; i < 4; i++) {
            float4 a = *(const float4*)(&a_lds[i][k]);
            acc[i][0] = fmaf(a.x, w00, acc[i][0]); acc[i][0] = fmaf(a.y, w10, acc[i][0]);
            acc[i][0] = fmaf(a.z, w20, acc[i][0]); acc[i][0] = fmaf(a.w, w30, acc[i][0]);
            acc[i][1] = fmaf(a.x, w01, acc[i][1]); acc[i][1] = fmaf(a.y, w11, acc[i][1]);
            acc[i][1] = fmaf(a.z, w21, acc[i][1]); acc[i][1] = fmaf(a.w, w31, acc[i][1]);
        }
    }
    if (kh == 1) {
#pragma unroll
        for (int i = 0; i < 4; i++) { pr[i][j] = acc[i][0]; pr[i][j + 256] = acc[i][1]; }
    }
    __syncthreads();
    if (kh == 0) {
        const float b0 = b_enc[j], b1 = b_enc[j + 256];
#pragma unroll
        for (int i = 0; i < 4; i++) {
            e_out[(size_t)(mb + i) * JH_ + j]       = acc[i][0] + pr[i][j] + b0;
            e_out[(size_t)(mb + i) * JH_ + j + 256] = acc[i][1] + pr[i][j + 256] + b1;
        }
    }
}

// ---------------- P2: p = dec^T @ W_pred + b_pred -> [B*U, JH] fp32 ----------
__global__ __launch_bounds__(512) void pred_proj(const float* __restrict__ dec,
                                                 const float* __restrict__ W_pred,
                                                 const float* __restrict__ b_pred,
                                                 float* __restrict__ p_out) {
    __shared__ float a_lds[4][PH_];
    __shared__ float pr[4][JH_];
    const int tid = threadIdx.x;
    const int mb = blockIdx.x * 4;   // rows m = b*U + u
    const int b  = mb >> 7;          // /U_
    const int u0 = mb & (U_ - 1);
    if (tid < PH_) {
        const float* src = dec + ((size_t)(b * PH_ + tid) * U_ + u0);
        float4 v0 = *(const float4*)(src);
        a_lds[0][tid] = v0.x; a_lds[1][tid] = v0.y; a_lds[2][tid] = v0.z; a_lds[3][tid] = v0.w;
    }
    __syncthreads();
    const int j  = tid & 255;
    const int kh = tid >> 8;
    const int kbase = kh * 160;
    float acc[4][2] = {{0.f, 0.f}, {0.f, 0.f}, {0.f, 0.f}, {0.f, 0.f}};
    for (int k4 = 0; k4 < 40; k4++) {
        const int k = kbase + k4 * 4;
        float w00 = W_pred[(k + 0) * JH_ + j], w01 = W_pred[(k + 0) * JH_ + j + 256];
        float w10 = W_pred[(k + 1) * JH_ + j], w11 = W_pred[(k + 1) * JH_ + j + 256];
        float w20 = W_pred[(k + 2) * JH_ + j], w21 = W_pred[(k + 2) * JH_ + j + 256];
        float w30 = W_pred[(k + 3) * JH_ + j], w31 = W_pred[(k + 3) * JH_ + j + 256];
#pragma unroll
        for (int i = 0; i < 4; i++) {
            float4 a = *(const float4*)(&a_lds[i][k]);
            acc[i][0] = fmaf(a.x, w00, acc[i][0]); acc[i][0] = fmaf(a.y, w10, acc[i][0]);
            acc[i][0] = fmaf(a.z, w20, acc[i][0]); acc[i][0] = fmaf(a.w, w30, acc[i][0]);
            acc[i][1] = fmaf(a.x, w01, acc[i][1]); acc[i][1] = fmaf(a.y, w11, acc[i][1]);
            acc[i][1] = fmaf(a.z, w21, acc[i][1]); acc[i][1] = fmaf(a.w, w31, acc[i][1]);
        }
    }
    if (kh == 1) {
#pragma unroll
        for (int i = 0; i < 4; i++) { pr[i][j] = acc[i][0]; pr[i][j + 256] = acc[i][1]; }
    }
    __syncthreads();
    if (kh == 0) {
        const float b0 = b_pred[j], b1 = b_pred[j + 256];
#pragma unroll
        for (int i = 0; i < 4; i++) {
            p_out[(size_t)(mb + i) * JH_ + j]       = acc[i][0] + pr[i][j] + b0;
            p_out[(size_t)(mb + i) * JH_ + j + 256] = acc[i][1] + pr[i][j + 256] + b1;
        }
    }
}

// ---------------- P3: WT2 = swizzled bf16 W_out for coalesced B-frag loads ---
// Main region (cols 0..1023), ushort index:
//   ((c>>4)*16 + (k>>5))*512 + ((k>>3)&3)*128 + (c&15)*8 + (k&7)
// Tail region at offset 524288: plain row for col 1024 (WTrow[k]).
__global__ __launch_bounds__(256) void wt_prep(const float* __restrict__ W_out,
                                               unsigned short* __restrict__ WT2) {
    const int idx = blockIdx.x * 256 + threadIdx.x;   // [0, 524288)
    const int k = idx >> 10;
    const int c = idx & 1023;
    const float v = W_out[(size_t)k * NC_ + c];
    const int dst = ((c >> 4) * 16 + (k >> 5)) * 512 +
                    ((k >> 3) & 3) * 128 + (c & 15) * 8 + (k & 7);
    WT2[dst] = f2bf(v);
    if (idx < JH_) WT2[524288 + idx] = f2bf(W_out[(size_t)idx * NC_ + (NC_ - 1)]);
}

// ---- inner K-loop over one 256-wide k-phase of h (8 steps of K=32) ----------
__device__ __forceinline__ void kloop(const unsigned short* __restrict__ hb,
                                      const unsigned short* __restrict__ wt_wave,
                                      int ph, int ln, int qd,
                                      floatx4 (&acc)[4][8]) {
#pragma unroll
    for (int ks = 0; ks < 8; ks++) {
        const int k0l = ks * 32;
        const int kb = ph * 8 + ks;
        short8 a[4];
#pragma unroll
        for (int i = 0; i < 4; i++) {
            int m = i * 16 + ln;
            int pc = ((k0l >> 3) + qd) ^ (m & 7);
            a[i] = *(const short8*)(hb + m * 256 + pc * 8);
        }
        __builtin_amdgcn_s_setprio(1);
#pragma unroll
        for (int nt = 0; nt < 8; nt++) {
            const short8 bfrag = *(const short8*)(wt_wave + (size_t)nt * 8192 + kb * 512);
#pragma unroll
            for (int i = 0; i < 4; i++)
                acc[i][nt] = __builtin_amdgcn_mfma_f32_16x16x32_bf16(
                        a[i], bfrag, acc[i][nt], 0, 0, 0);
        }
        __builtin_amdgcn_s_setprio(0);
    }
}

// ---- convert pre-loaded p regs -> relu(e+p) bf16 into h buffer; fold col-1024
__device__ __forceinline__ void stage8(unsigned short* __restrict__ hst,
                                       const float4 e4, const float4* pv,
                                       const unsigned short* __restrict__ w1024,
                                       float* c_acc) {
    short4v wv = *(const short4v*)(w1024);
    const float w0 = bf2f((unsigned short)wv[0]);
    const float w1 = bf2f((unsigned short)wv[1]);
    const float w2 = bf2f((unsigned short)wv[2]);
    const float w3 = bf2f((unsigned short)wv[3]);
#pragma unroll
    for (int it = 0; it < 8; it++) {
        float hx = fmaxf(e4.x + pv[it].x, 0.f);
        float hy = fmaxf(e4.y + pv[it].y, 0.f);
        float hz = fmaxf(e4.z + pv[it].z, 0.f);
        float hw_ = fmaxf(e4.w + pv[it].w, 0.f);
        c_acc[it] = fmaf(hx, w0, c_acc[it]);
        c_acc[it] = fmaf(hy, w1, c_acc[it]);
        c_acc[it] = fmaf(hz, w2, c_acc[it]);
        c_acc[it] = fmaf(hw_, w3, c_acc[it]);
        short4v hv;
        hv[0] = (short)f2bf(hx); hv[1] = (short)f2bf(hy);
        hv[2] = (short)f2bf(hz); hv[3] = (short)f2bf(hw_);
        *(short4v*)(hst + it * 2048) = hv;   // it*8 rows * 256 ushorts
    }
}

// ---------------- Main fused joint: logits + log_softmax, single pass --------
// grid = 2048 blocks x 512 threads (8 waves, 1 block/CU at 256-reg class).
// Double-buffered h (T14 reg-staged prefetch), col-1024 folded into staging,
// double-buffered dense-write epilogue.
__global__ __launch_bounds__(512, 2) void joint_kernel(
        const float* __restrict__ e, const float* __restrict__ p,
        const unsigned short* __restrict__ WT2,
        const float* __restrict__ b_out, float* __restrict__ out) {
    __shared__ __align__(16) char hs_buf[65600];   // h0 | h1 ; aliased s0 | s1
    __shared__ float stripes[8][64];
    __shared__ float rowmax_lds[64];
    __shared__ float lse_lds[64];
    __shared__ float c1024_lds[64];
    unsigned short* h0 = (unsigned short*)hs_buf;            // [64][256] swizzled
    unsigned short* h1 = (unsigned short*)(hs_buf + 32800);
    float* s0 = (float*)hs_buf;                              // [8][1025] f32
    float* s1 = (float*)(hs_buf + 32800);

    const int tid = threadIdx.x;
    const int m0 = blockIdx.x * 64;
    const int bb = m0 >> 15;             // /(T*U)
    const int tt = (m0 >> 7) & (T_ - 1);
    const int u0 = m0 & (U_ - 1);        // 0 or 64

    const int wave = tid >> 6;
    const int lane = tid & 63;
    const int qd = lane >> 4;
    const int ln = lane & 15;
    const int n0 = wave << 7;

    floatx4 acc[4][8];
#pragma unroll
    for (int i = 0; i < 4; i++)
#pragma unroll
        for (int nt = 0; nt < 8; nt++) acc[i][nt] = (floatx4){0.f, 0.f, 0.f, 0.f};

    const float* e_row = e + (size_t)(bb * T_ + tt) * JH_;
    const float* p_base = p + (size_t)(bb * U_ + u0) * JH_;
    const unsigned short* wt_wave = WT2 + (size_t)wave * 65536 + lane * 8;
    const unsigned short* wt_c1024 = WT2 + 524288;

    // staging thread mapping: kq = lane (k-quad), rslot = wave (row mod 8)
    const int kq = lane;
    const int rslot = wave;
    const int hoff = rslot * 256 + (((kq >> 1) ^ rslot) * 8) + (kq & 1) * 4;

    float c_acc[8] = {0.f, 0.f, 0.f, 0.f, 0.f, 0.f, 0.f, 0.f};

    // ---- phase 0 stage (not overlapped; first touch) ----
    {
        float4 pva[8];
        const float* pp = p_base + rslot * JH_ + kq * 4;
#pragma unroll
        for (int it = 0; it < 8; it++) pva[it] = *(const float4*)(pp + it * 8 * JH_);
        const float4 e4a = *(const float4*)(e_row + kq * 4);
        stage8(h0 + hoff, e4a, pva, wt_c1024 + kq * 4, c_acc);
    }
    __syncthreads();

    // ---- issue phase-1 loads (hide under phase-0 MFMA) ----
    float4 pvb[8];
    {
        const float* pp = p_base + rslot * JH_ + 256 + kq * 4;
#pragma unroll
        for (int it = 0; it < 8; it++) pvb[it] = *(const float4*)(pp + it * 8 * JH_);
    }
    const float4 e4b = *(const float4*)(e_row + 256 + kq * 4);

    kloop(h0, wt_wave, 0, ln, qd, acc);

    stage8(h1 + hoff, e4b, pvb, wt_c1024 + 256 + kq * 4, c_acc);
    __syncthreads();

    // preload bias while MFMA runs
    float brow[8];
#pragma unroll
    for (int nt = 0; nt < 8; nt++) brow[nt] = b_out[n0 + nt * 16 + ln];

    kloop(h1, wt_wave, 1, ln, qd, acc);

    // ---- col-1024: butterfly the per-thread k-partials (wave = row group) ----
#pragma unroll
    for (int it = 0; it < 8; it++) {
        float v = c_acc[it];
        v += __shfl_xor(v, 1);  v += __shfl_xor(v, 2);  v += __shfl_xor(v, 4);
        v += __shfl_xor(v, 8);  v += __shfl_xor(v, 16); v += __shfl_xor(v, 32);
        if (lane == 0) c1024_lds[it * 8 + wave] = v + b_out[NC_ - 1];
    }

    // ---- bias add ----
#pragma unroll
    for (int nt = 0; nt < 8; nt++) {
#pragma unroll
        for (int i = 0; i < 4; i++) {
            acc[i][nt][0] += brow[nt]; acc[i][nt][1] += brow[nt];
            acc[i][nt][2] += brow[nt]; acc[i][nt][3] += brow[nt];
        }
    }

    // ---- row max ----
    float mx[4][4];
#pragma unroll
    for (int i = 0; i < 4; i++)
#pragma unroll
        for (int r = 0; r < 4; r++) {
            float m = acc[i][0][r];
#pragma unroll
            for (int nt = 1; nt < 8; nt++) m = fmaxf(m, acc[i][nt][r]);
            m = fmaxf(m, __shfl_xor(m, 1, 16));
            m = fmaxf(m, __shfl_xor(m, 2, 16));
            m = fmaxf(m, __shfl_xor(m, 4, 16));
            m = fmaxf(m, __shfl_xor(m, 8, 16));
            mx[i][r] = m;
        }
    if (ln == 0) {
#pragma unroll
        for (int i = 0; i < 4; i++)
#pragma unroll
            for (int r = 0; r < 4; r++)
                stripes[wave][i * 16 + qd * 4 + r] = mx[i][r];
    }
    __syncthreads();
    if (tid < 64) {
        float m = c1024_lds[tid];
#pragma unroll
        for (int w = 0; w < 8; w++) m = fmaxf(m, stripes[w][tid]);
        rowmax_lds[tid] = m;
    }
    __syncthreads();

    // ---- sum of exp ----
#pragma unroll
    for (int i = 0; i < 4; i++)
#pragma unroll
        for (int r = 0; r < 4; r++) {
            float rm = rowmax_lds[i * 16 + qd * 4 + r];
            float s = 0.f;
#pragma unroll
            for (int nt = 0; nt < 8; nt++) s += __expf(acc[i][nt][r] - rm);
            s += __shfl_xor(s, 1, 16);
            s += __shfl_xor(s, 2, 16);
            s += __shfl_xor(s, 4, 16);
            s += __shfl_xor(s, 8, 16);
            mx[i][r] = s;
        }
    if (ln == 0) {
#pragma unroll
        for (int i = 0; i < 4; i++)
#pragma unroll
            for (int r = 0; r < 4; r++)
                stripes[wave][i * 16 + qd * 4 + r] = mx[i][r];
    }
    __syncthreads();
    if (tid < 64) {
        float rm = rowmax_lds[tid];
        float s = __expf(c1024_lds[tid] - rm);
#pragma unroll
        for (int w = 0; w < 8; w++) s += stripes[w][tid];
        lse_lds[tid] = rm + __logf(s);
    }
    __syncthreads();

    // ---- epilogue: double-buffered {unpack 8 rows -> LDS, dense f4 NT copy} --
    // unpack(c): rows [8c,8c+8) of normalized logits into a stage buffer
    // copy(c):   that 32,800 B contiguous span -> out (2050 line-aligned f4)
#define UNPACK(c, dst)                                                          \
    {                                                                           \
        const int i_ = (c) >> 1;                                                \
        if ((qd >> 1) == ((c) & 1)) {                                           \
            _Pragma("unroll")                                                   \
            for (int r = 0; r < 4; r++) {                                       \
                const int lr = (qd & 1) * 4 + r;                                \
                const float l = lse_lds[(c) * 8 + lr];                          \
                _Pragma("unroll")                                               \
                for (int nt = 0; nt < 8; nt++)                                  \
                    (dst)[lr * NC_ + n0 + nt * 16 + ln] = acc[i_][nt][r] - l;   \
            }                                                                   \
        }                                                                       \
        if (tid < 8)                                                            \
            (dst)[tid * NC_ + 1024] = c1024_lds[(c) * 8 + tid] - lse_lds[(c) * 8 + tid]; \
    }
#define COPYOUT(c, src)                                                         \
    {                                                                           \
        const floatx4* s4_ = (const floatx4*)(src);                             \
        floatx4* d4_ = (floatx4*)(out + (size_t)(m0 + (c) * 8) * NC_);          \
        for (int j_ = tid; j_ < 2050; j_ += 512)                                \
            __builtin_nontemporal_store(s4_[j_], d4_ + j_);                     \
    }

    UNPACK(0, s0);
    __syncthreads();
#pragma unroll
    for (int c = 1; c < 8; c++) {
        float* rd = (c & 1) ? s0 : s1;   // buffer holding chunk c-1
        float* wr = (c & 1) ? s1 : s0;   // buffer for chunk c
        COPYOUT(c - 1, rd);
        UNPACK(c, wr);
        __syncthreads();
    }
    COPYOUT(7, s1);
#undef UNPACK
#undef COPYOUT
}

extern "C" void kernel_launch(void* const* d_in, const int* in_sizes, int n_in,
                              void* d_out, int out_size, void* d_ws, size_t ws_size,
                              hipStream_t stream) {
    const float* enc    = (const float*)d_in[0];
    const float* dec    = (const float*)d_in[1];
    const float* W_enc  = (const float*)d_in[2];
    const float* b_enc  = (const float*)d_in[3];
    const float* W_pred = (const float*)d_in[4];
    const float* b_pred = (const float*)d_in[5];
    const float* W_out  = (const float*)d_in[6];
    const float* b_out  = (const float*)d_in[7];
    float* out = (float*)d_out;

    char* ws = (char*)d_ws;
    float* e_buf = (float*)ws;                                 // 2 MiB: [1024][512] f32
    float* p_buf = (float*)(ws + (2u << 20));                  // 1 MiB: [512][512] f32
    unsigned short* WT2 = (unsigned short*)(ws + (3u << 20));  // ~1 MiB swizzled + col-1024 row

    enc_proj<<<dim3(256), dim3(512), 0, stream>>>(enc, W_enc, b_enc, e_buf);
    pred_proj<<<dim3(128), dim3(512), 0, stream>>>(dec, W_pred, b_pred, p_buf);
    wt_prep<<<dim3(2048), dim3(256), 0, stream>>>(W_out, WT2);
    joint_kernel<<<dim3(2048), dim3(512), 0, stream>>>(e_buf, p_buf, WT2, b_out, out);
}